// Round 2
// baseline (2376.502 us; speedup 1.0000x reference)
//
#include <hip/hip_runtime.h>
#include <cstdint>
#include <cstddef>

// ---------------------------------------------------------------------------
// EncoderBlock: pre-norm MHA + pre-norm MLP, B=4 S=2048 D=2048 H=16 HD=128 DFF=8192
// All GEMMs via bf16 MFMA 16x16x32 (m97-style 128x128 tile, global_load_lds w=16).
// Attention: per-wave flash kernel, 16-row Q tiles, 32-key K tiles.
// Workspace plan (stream-order buffer reuse, peak 200 MB):
//   [0,8)    W8   : wqT/wkT/wvT/woT, sequentially
//   [8,40)   W32  : fc1T then fc2T
//   [40,72)  act  : h -> attnO -> h2
//   [72,104) qb   | [104,136) kb | [136,168) vb | [168,200) vtb
//   [72,200) mid  (overlays q/k/v/vt after attention)
//   x1 (x + attn proj, fp32) lives in d_out.
// ---------------------------------------------------------------------------

typedef __attribute__((ext_vector_type(8))) __bf16 bf16x8;
typedef __attribute__((ext_vector_type(4))) float f32x4;

#define MFMA16(a, b, c) __builtin_amdgcn_mfma_f32_16x16x32_bf16((a), (b), (c), 0, 0, 0)

__device__ __forceinline__ unsigned short f2bf(float f) {
    unsigned int u = __builtin_bit_cast(unsigned int, f);
    u = (u + 0x7FFFu + ((u >> 16) & 1u)) >> 16;   // RNE
    return (unsigned short)u;
}

__device__ __forceinline__ void async16(const void* gptr, void* lptr) {
    __builtin_amdgcn_global_load_lds(
        (const __attribute__((address_space(1))) void*)gptr,
        (__attribute__((address_space(3))) void*)lptr, 16, 0, 0);
}

// ---------------------------------------------------------------------------
// Weight transpose + fp32->bf16 cast:  W[K][N] fp32  ->  WT[N][K] bf16
// ---------------------------------------------------------------------------
__global__ void transpose_f32_bf16(const float* __restrict__ W,
                                   unsigned short* __restrict__ WT, int K, int N) {
    __shared__ float t[32][33];
    const int n0 = blockIdx.x * 32, k0 = blockIdx.y * 32;
    const int tx = threadIdx.x, ty = threadIdx.y;
#pragma unroll
    for (int i = 0; i < 4; ++i)
        t[ty + i * 8][tx] = W[(size_t)(k0 + ty + i * 8) * N + n0 + tx];
    __syncthreads();
#pragma unroll
    for (int i = 0; i < 4; ++i)
        WT[(size_t)(n0 + ty + i * 8) * K + k0 + tx] = f2bf(t[tx][ty + i * 8]);
}

// per-(b,h) bf16 transpose: V [BH][2048][128] -> VT [BH][128][2048]
__global__ void transpose_v_bh(const unsigned short* __restrict__ V,
                               unsigned short* __restrict__ VT) {
    __shared__ unsigned short t[32][33];
    const int bh = blockIdx.z;
    const unsigned short* src = V + (size_t)bh * 2048 * 128;
    unsigned short* dst = VT + (size_t)bh * 128 * 2048;
    const int n0 = blockIdx.x * 32;   // hd
    const int k0 = blockIdx.y * 32;   // s
    const int tx = threadIdx.x, ty = threadIdx.y;
#pragma unroll
    for (int i = 0; i < 4; ++i)
        t[ty + i * 8][tx] = src[(size_t)(k0 + ty + i * 8) * 128 + n0 + tx];
    __syncthreads();
#pragma unroll
    for (int i = 0; i < 4; ++i)
        dst[(size_t)(n0 + ty + i * 8) * 2048 + k0 + tx] = t[tx][ty + i * 8];
}

// ---------------------------------------------------------------------------
// LayerNorm over D=2048, one 256-thread block per row, fp32 in -> bf16 out
// ---------------------------------------------------------------------------
__global__ void __launch_bounds__(256)
ln_kernel(const float* __restrict__ x, const float* __restrict__ w,
          const float* __restrict__ b, unsigned short* __restrict__ out) {
    const int row = blockIdx.x;
    const int tid = threadIdx.x;
    const float* xr = x + (size_t)row * 2048;
    float4 v0 = *reinterpret_cast<const float4*>(xr + tid * 8);
    float4 v1 = *reinterpret_cast<const float4*>(xr + tid * 8 + 4);
    float vv[8] = {v0.x, v0.y, v0.z, v0.w, v1.x, v1.y, v1.z, v1.w};
    float s = 0.f, q = 0.f;
#pragma unroll
    for (int j = 0; j < 8; ++j) { s += vv[j]; q += vv[j] * vv[j]; }
#pragma unroll
    for (int off = 32; off >= 1; off >>= 1) {
        s += __shfl_down(s, off);
        q += __shfl_down(q, off);
    }
    __shared__ float red[8];
    const int lane = tid & 63, wv = tid >> 6;
    if (lane == 0) { red[wv] = s; red[4 + wv] = q; }
    __syncthreads();
    s = red[0] + red[1] + red[2] + red[3];
    q = red[4] + red[5] + red[6] + red[7];
    const float mu = s * (1.f / 2048.f);
    const float var = q * (1.f / 2048.f) - mu * mu;
    const float rstd = rsqrtf(var + 1e-5f);
    alignas(16) unsigned short pk[8];
    const float* wp = w + tid * 8;
    const float* bp = b + tid * 8;
#pragma unroll
    for (int j = 0; j < 8; ++j)
        pk[j] = f2bf((vv[j] - mu) * rstd * wp[j] + bp[j]);
    *reinterpret_cast<uint4*>(out + (size_t)row * 2048 + tid * 8) =
        *reinterpret_cast<const uint4*>(pk);
}

// ---------------------------------------------------------------------------
// GEMM: C[M,N] = A[M,K] @ BT[N,K]^T   (A,BT bf16 row-major)
// 128x128 tile, BK=64, 4 waves (2x2 of 64x64), 16x16x32 MFMA.
// Epilogues: 0 = bf16 head-layout [B,H,S,HD] with scale (QKV)
//            1 = fp32 resid + acc                         (O-proj)
//            2 = bf16 gelu_new(acc + bias)                (FC1)
//            3 = fp32 acc + bias + resid (in-place ok)    (FC2)
// ---------------------------------------------------------------------------
template <int EPI>
__global__ void __launch_bounds__(256)
gemm_bt(const unsigned short* __restrict__ A, const unsigned short* __restrict__ BT,
        int M, int N, int K,
        const float* __restrict__ bias, const float* __restrict__ resid,
        float* __restrict__ outF, unsigned short* __restrict__ outB, float scale) {
    __shared__ __align__(16) unsigned short lds[2 * 128 * 64];
    unsigned short* lA = lds;
    unsigned short* lB = lds + 128 * 64;
    const int tid = threadIdx.x;
    const int lane = tid & 63;
    const int w = tid >> 6;
    const int wm = (w >> 1) * 64;
    const int wn = (w & 1) * 64;
    const int m0 = blockIdx.y * 128;
    const int n0 = blockIdx.x * 128;
    const int g = lane >> 4, lr = lane & 15;

    f32x4 acc[4][4];
#pragma unroll
    for (int i = 0; i < 4; ++i)
#pragma unroll
        for (int j = 0; j < 4; ++j)
            acc[i][j] = (f32x4){0.f, 0.f, 0.f, 0.f};

    // staging: LDS row r, slot s holds global chunk col (s - r) & 7  (swizzle)
    int rr[4], cc[4];
#pragma unroll
    for (int c = 0; c < 4; ++c) {
        const int chunk = tid + c * 256;
        rr[c] = chunk >> 3;
        cc[c] = (((chunk & 7) - rr[c]) & 7) * 8;
    }

    for (int k0 = 0; k0 < K; k0 += 64) {
        __syncthreads();
#pragma unroll
        for (int c = 0; c < 4; ++c) {
            async16(&A[(size_t)(m0 + rr[c]) * K + k0 + cc[c]], &lA[(size_t)(tid + c * 256) * 8]);
            async16(&BT[(size_t)(n0 + rr[c]) * K + k0 + cc[c]], &lB[(size_t)(tid + c * 256) * 8]);
        }
        __syncthreads();
#pragma unroll
        for (int ks = 0; ks < 2; ++ks) {
            bf16x8 af[4], bfr[4];
            const int cA = ks * 4 + g;
#pragma unroll
            for (int i = 0; i < 4; ++i) {
                const int rA = wm + i * 16 + lr;
                af[i] = *reinterpret_cast<const bf16x8*>(&lA[(rA * 8 + ((cA + rA) & 7)) * 8]);
                const int rB = wn + i * 16 + lr;
                bfr[i] = *reinterpret_cast<const bf16x8*>(&lB[(rB * 8 + ((cA + rB) & 7)) * 8]);
            }
#pragma unroll
            for (int mb = 0; mb < 4; ++mb)
#pragma unroll
                for (int nb = 0; nb < 4; ++nb)
                    acc[mb][nb] = MFMA16(af[mb], bfr[nb], acc[mb][nb]);
        }
    }

    // epilogue: C row = m0+wm+mb*16+g*4+r, col = n0+wn+nb*16+lr
#pragma unroll
    for (int mb = 0; mb < 4; ++mb) {
#pragma unroll
        for (int r = 0; r < 4; ++r) {
            const int m = m0 + wm + mb * 16 + g * 4 + r;
#pragma unroll
            for (int nb = 0; nb < 4; ++nb) {
                const int n = n0 + wn + nb * 16 + lr;
                float v = acc[mb][nb][r];
                if constexpr (EPI == 0) {
                    v *= scale;
                    const int b = m >> 11, s = m & 2047;
                    const int h = n >> 7, hd = n & 127;
                    outB[(((size_t)(b * 16 + h) * 2048 + s) << 7) + hd] = f2bf(v);
                } else if constexpr (EPI == 1) {
                    const size_t idx = (size_t)m * N + n;
                    outF[idx] = resid[idx] + v;
                } else if constexpr (EPI == 2) {
                    v += bias[n];
                    const float u = 0.7978845608028654f * (v + 0.044715f * v * v * v);
                    const float ge = 0.5f * v * (1.f + tanhf(u));
                    outB[(size_t)m * N + n] = f2bf(ge);
                } else {
                    const size_t idx = (size_t)m * N + n;
                    outF[idx] = v + bias[n] + resid[idx];
                }
            }
        }
    }
}

// ---------------------------------------------------------------------------
// Flash attention: 1 wave per (bh, 16-row q-tile). Q,K in [B,H,S,HD] bf16
// (Q pre-scaled by 1/sqrt(HD)), V in [B,H,HD,S] bf16. O -> [B,S,D] bf16.
// ---------------------------------------------------------------------------
__global__ void __launch_bounds__(64)
attn_kernel(const unsigned short* __restrict__ Q, const unsigned short* __restrict__ Kt,
            const unsigned short* __restrict__ VT, unsigned short* __restrict__ O) {
    __shared__ __align__(16) unsigned short Pl[16 * 32];
    const int bh = blockIdx.y;
    const int qt = blockIdx.x;
    const int lane = threadIdx.x;
    const int g = lane >> 4, lr = lane & 15;
    const unsigned short* Qp = Q + ((size_t)bh * 2048 + qt * 16) * 128;
    const unsigned short* Kp = Kt + (size_t)bh * 2048 * 128;
    const unsigned short* Vp = VT + (size_t)bh * 128 * 2048;

    bf16x8 qf[4];
#pragma unroll
    for (int kd = 0; kd < 4; ++kd)
        qf[kd] = *reinterpret_cast<const bf16x8*>(&Qp[lr * 128 + kd * 32 + g * 8]);

    f32x4 o[8];
#pragma unroll
    for (int db = 0; db < 8; ++db) o[db] = (f32x4){0.f, 0.f, 0.f, 0.f};
    float mm[4] = {-1e30f, -1e30f, -1e30f, -1e30f};
    float ll[4] = {0.f, 0.f, 0.f, 0.f};

    for (int kt = 0; kt < 64; ++kt) {
        const int kb = kt * 32;
        f32x4 s0 = (f32x4){0.f, 0.f, 0.f, 0.f};
        f32x4 s1 = (f32x4){0.f, 0.f, 0.f, 0.f};
#pragma unroll
        for (int kd = 0; kd < 4; ++kd) {
            bf16x8 k0f = *reinterpret_cast<const bf16x8*>(&Kp[(size_t)(kb + lr) * 128 + kd * 32 + g * 8]);
            bf16x8 k1f = *reinterpret_cast<const bf16x8*>(&Kp[(size_t)(kb + 16 + lr) * 128 + kd * 32 + g * 8]);
            s0 = MFMA16(qf[kd], k0f, s0);
            s1 = MFMA16(qf[kd], k1f, s1);
        }
        float al[4], p0v[4], p1v[4];
#pragma unroll
        for (int r = 0; r < 4; ++r) {
            float mx = fmaxf(s0[r], s1[r]);
            mx = fmaxf(mx, __shfl_xor(mx, 1));
            mx = fmaxf(mx, __shfl_xor(mx, 2));
            mx = fmaxf(mx, __shfl_xor(mx, 4));
            mx = fmaxf(mx, __shfl_xor(mx, 8));
            const float nm = fmaxf(mm[r], mx);
            al[r] = __expf(mm[r] - nm);
            p0v[r] = __expf(s0[r] - nm);
            p1v[r] = __expf(s1[r] - nm);
            float rs = p0v[r] + p1v[r];
            rs += __shfl_xor(rs, 1);
            rs += __shfl_xor(rs, 2);
            rs += __shfl_xor(rs, 4);
            rs += __shfl_xor(rs, 8);
            ll[r] = ll[r] * al[r] + rs;
            mm[r] = nm;
        }
#pragma unroll
        for (int db = 0; db < 8; ++db) {
            o[db][0] *= al[0]; o[db][1] *= al[1];
            o[db][2] *= al[2]; o[db][3] *= al[3];
        }
        __syncthreads();
#pragma unroll
        for (int r = 0; r < 4; ++r) {
            Pl[(g * 4 + r) * 32 + lr] = f2bf(p0v[r]);
            Pl[(g * 4 + r) * 32 + 16 + lr] = f2bf(p1v[r]);
        }
        __syncthreads();
        bf16x8 pf = *reinterpret_cast<const bf16x8*>(&Pl[lr * 32 + g * 8]);
#pragma unroll
        for (int db = 0; db < 8; ++db) {
            bf16x8 vf = *reinterpret_cast<const bf16x8*>(&Vp[(size_t)(db * 16 + lr) * 2048 + kb + g * 8]);
            o[db] = MFMA16(pf, vf, o[db]);
        }
    }
    const int b = bh >> 4, h = bh & 15;
#pragma unroll
    for (int db = 0; db < 8; ++db)
#pragma unroll
        for (int r = 0; r < 4; ++r) {
            const int s = qt * 16 + g * 4 + r;
            const float v = o[db][r] / ll[r];
            O[((size_t)(b * 2048 + s)) * 2048 + h * 128 + db * 16 + lr] = f2bf(v);
        }
}

// ---------------------------------------------------------------------------
extern "C" void kernel_launch(void* const* d_in, const int* in_sizes, int n_in,
                              void* d_out, int out_size, void* d_ws, size_t ws_size,
                              hipStream_t stream) {
    const float* x    = (const float*)d_in[0];
    const float* wq   = (const float*)d_in[1];
    const float* wk   = (const float*)d_in[2];
    const float* wv   = (const float*)d_in[3];
    const float* wo   = (const float*)d_in[4];
    const float* ln1w = (const float*)d_in[5];
    const float* ln1b = (const float*)d_in[6];
    const float* ln2w = (const float*)d_in[7];
    const float* ln2b = (const float*)d_in[8];
    const float* fc1w = (const float*)d_in[9];
    const float* fc1b = (const float*)d_in[10];
    const float* fc2w = (const float*)d_in[11];
    const float* fc2b = (const float*)d_in[12];
    float* out = (float*)d_out;

    const size_t MB = 1024ull * 1024ull;
    const size_t NEED = 200 * MB;
    if (ws_size < NEED) return;  // diagnostic: clean absmax-fail instead of OOB crash

    char* ws = (char*)d_ws;
    unsigned short* W8   = (unsigned short*)(ws + 0 * MB);    //  8 MB: wqT/wkT/wvT/woT (seq.)
    unsigned short* W32  = (unsigned short*)(ws + 8 * MB);    // 32 MB: fc1T then fc2T
    unsigned short* act  = (unsigned short*)(ws + 40 * MB);   // 32 MB: h -> attnO -> h2
    unsigned short* qb   = (unsigned short*)(ws + 72 * MB);   // 32 MB
    unsigned short* kb   = (unsigned short*)(ws + 104 * MB);  // 32 MB
    unsigned short* vb   = (unsigned short*)(ws + 136 * MB);  // 32 MB
    unsigned short* vtb  = (unsigned short*)(ws + 168 * MB);  // 32 MB
    unsigned short* mid  = qb;                                // 128 MB overlay (post-attn)
    float*          x1   = out;                               // x + attn proj lives in d_out

    const dim3 tb(32, 8);
    const float qscale = 0.08838834764831845f;

    // LN1: x -> h (bf16)
    ln_kernel<<<8192, 256, 0, stream>>>(x, ln1w, ln1b, act);

    // Q = h @ wq (scaled), head layout
    transpose_f32_bf16<<<dim3(64, 64), tb, 0, stream>>>(wq, W8, 2048, 2048);
    gemm_bt<0><<<dim3(16, 64), 256, 0, stream>>>(act, W8, 8192, 2048, 2048,
                                                 nullptr, nullptr, nullptr, qb, qscale);
    // K
    transpose_f32_bf16<<<dim3(64, 64), tb, 0, stream>>>(wk, W8, 2048, 2048);
    gemm_bt<0><<<dim3(16, 64), 256, 0, stream>>>(act, W8, 8192, 2048, 2048,
                                                 nullptr, nullptr, nullptr, kb, 1.f);
    // V
    transpose_f32_bf16<<<dim3(64, 64), tb, 0, stream>>>(wv, W8, 2048, 2048);
    gemm_bt<0><<<dim3(16, 64), 256, 0, stream>>>(act, W8, 8192, 2048, 2048,
                                                 nullptr, nullptr, nullptr, vb, 1.f);

    // V -> V^T per (b,h)
    transpose_v_bh<<<dim3(4, 64, 64), tb, 0, stream>>>(vb, vtb);

    // attention -> act ([B,S,D] bf16)
    attn_kernel<<<dim3(128, 64), 64, 0, stream>>>(qb, kb, vtb, act);

    // O-proj + residual -> x1 (= d_out, fp32)
    transpose_f32_bf16<<<dim3(64, 64), tb, 0, stream>>>(wo, W8, 2048, 2048);
    gemm_bt<1><<<dim3(16, 64), 256, 0, stream>>>(act, W8, 8192, 2048, 2048,
                                                 nullptr, x, x1, nullptr, 1.f);

    // LN2: x1 -> h2 (bf16, into act)
    ln_kernel<<<8192, 256, 0, stream>>>(x1, ln2w, ln2b, act);

    // FC1 + bias + gelu_new -> mid (bf16)
    transpose_f32_bf16<<<dim3(256, 64), tb, 0, stream>>>(fc1w, W32, 2048, 8192);
    gemm_bt<2><<<dim3(64, 64), 256, 0, stream>>>(act, W32, 8192, 8192, 2048,
                                                 fc1b, nullptr, nullptr, mid, 1.f);

    // FC2 + bias + residual(x1 in d_out) -> d_out (in-place RMW, one touch/elem)
    transpose_f32_bf16<<<dim3(64, 256), tb, 0, stream>>>(fc2w, W32, 8192, 2048);
    gemm_bt<3><<<dim3(16, 64), 256, 0, stream>>>(mid, W32, 8192, 2048, 8192,
                                                 fc2b, x1, out, nullptr, 1.f);
}

// Round 3
// 1631.700 us; speedup vs baseline: 1.4565x; 1.4565x over previous
//
#include <hip/hip_runtime.h>
#include <cstdint>
#include <cstddef>

// ---------------------------------------------------------------------------
// EncoderBlock: pre-norm MHA + pre-norm MLP, B=4 S=2048 D=2048 H=16 HD=128 DFF=8192
// GEMMs: bf16 MFMA 16x16x32, 128x128 tile, global_load_lds w=16 (m97 recipe).
// Attention (R2): FA2-style block = 4 waves, Q-tile 64 rows, K-tile 64 keys
// staged in LDS (shared across waves), XOR-swizzled LDS to kill bank conflicts.
// Workspace plan (stream-order reuse, peak 200 MB); x1 lives in d_out.
// ---------------------------------------------------------------------------

typedef __attribute__((ext_vector_type(8))) __bf16 bf16x8;
typedef __attribute__((ext_vector_type(4))) float f32x4;

#define MFMA16(a, b, c) __builtin_amdgcn_mfma_f32_16x16x32_bf16((a), (b), (c), 0, 0, 0)

__device__ __forceinline__ unsigned short f2bf(float f) {
    unsigned int u = __builtin_bit_cast(unsigned int, f);
    u = (u + 0x7FFFu + ((u >> 16) & 1u)) >> 16;   // RNE
    return (unsigned short)u;
}

__device__ __forceinline__ void async16(const void* gptr, void* lptr) {
    __builtin_amdgcn_global_load_lds(
        (const __attribute__((address_space(1))) void*)gptr,
        (__attribute__((address_space(3))) void*)lptr, 16, 0, 0);
}

// ---------------------------------------------------------------------------
// Weight transpose + fp32->bf16 cast:  W[K][N] fp32  ->  WT[N][K] bf16
// ---------------------------------------------------------------------------
__global__ void transpose_f32_bf16(const float* __restrict__ W,
                                   unsigned short* __restrict__ WT, int K, int N) {
    __shared__ float t[32][33];
    const int n0 = blockIdx.x * 32, k0 = blockIdx.y * 32;
    const int tx = threadIdx.x, ty = threadIdx.y;
#pragma unroll
    for (int i = 0; i < 4; ++i)
        t[ty + i * 8][tx] = W[(size_t)(k0 + ty + i * 8) * N + n0 + tx];
    __syncthreads();
#pragma unroll
    for (int i = 0; i < 4; ++i)
        WT[(size_t)(n0 + ty + i * 8) * K + k0 + tx] = f2bf(t[tx][ty + i * 8]);
}

// per-(b,h) bf16 transpose: V [BH][2048][128] -> VT [BH][128][2048]
__global__ void transpose_v_bh(const unsigned short* __restrict__ V,
                               unsigned short* __restrict__ VT) {
    __shared__ unsigned short t[32][33];
    const int bh = blockIdx.z;
    const unsigned short* src = V + (size_t)bh * 2048 * 128;
    unsigned short* dst = VT + (size_t)bh * 128 * 2048;
    const int n0 = blockIdx.x * 32;   // hd
    const int k0 = blockIdx.y * 32;   // s
    const int tx = threadIdx.x, ty = threadIdx.y;
#pragma unroll
    for (int i = 0; i < 4; ++i)
        t[ty + i * 8][tx] = src[(size_t)(k0 + ty + i * 8) * 128 + n0 + tx];
    __syncthreads();
#pragma unroll
    for (int i = 0; i < 4; ++i)
        dst[(size_t)(n0 + ty + i * 8) * 2048 + k0 + tx] = t[tx][ty + i * 8];
}

// ---------------------------------------------------------------------------
// LayerNorm over D=2048, one 256-thread block per row, fp32 in -> bf16 out
// ---------------------------------------------------------------------------
__global__ void __launch_bounds__(256)
ln_kernel(const float* __restrict__ x, const float* __restrict__ w,
          const float* __restrict__ b, unsigned short* __restrict__ out) {
    const int row = blockIdx.x;
    const int tid = threadIdx.x;
    const float* xr = x + (size_t)row * 2048;
    float4 v0 = *reinterpret_cast<const float4*>(xr + tid * 8);
    float4 v1 = *reinterpret_cast<const float4*>(xr + tid * 8 + 4);
    float vv[8] = {v0.x, v0.y, v0.z, v0.w, v1.x, v1.y, v1.z, v1.w};
    float s = 0.f, q = 0.f;
#pragma unroll
    for (int j = 0; j < 8; ++j) { s += vv[j]; q += vv[j] * vv[j]; }
#pragma unroll
    for (int off = 32; off >= 1; off >>= 1) {
        s += __shfl_down(s, off);
        q += __shfl_down(q, off);
    }
    __shared__ float red[8];
    const int lane = tid & 63, wv = tid >> 6;
    if (lane == 0) { red[wv] = s; red[4 + wv] = q; }
    __syncthreads();
    s = red[0] + red[1] + red[2] + red[3];
    q = red[4] + red[5] + red[6] + red[7];
    const float mu = s * (1.f / 2048.f);
    const float var = q * (1.f / 2048.f) - mu * mu;
    const float rstd = rsqrtf(var + 1e-5f);
    alignas(16) unsigned short pk[8];
    const float* wp = w + tid * 8;
    const float* bp = b + tid * 8;
#pragma unroll
    for (int j = 0; j < 8; ++j)
        pk[j] = f2bf((vv[j] - mu) * rstd * wp[j] + bp[j]);
    *reinterpret_cast<uint4*>(out + (size_t)row * 2048 + tid * 8) =
        *reinterpret_cast<const uint4*>(pk);
}

// ---------------------------------------------------------------------------
// GEMM: C[M,N] = A[M,K] @ BT[N,K]^T   (A,BT bf16 row-major)
// 128x128 tile, BK=64, 4 waves (2x2 of 64x64), 16x16x32 MFMA.
// Epilogues: 0 = bf16 head-layout [B,H,S,HD] with scale (QKV)
//            1 = fp32 resid + acc                         (O-proj)
//            2 = bf16 gelu_new(acc + bias)                (FC1)
//            3 = fp32 acc + bias + resid (in-place ok)    (FC2)
// ---------------------------------------------------------------------------
template <int EPI>
__global__ void __launch_bounds__(256)
gemm_bt(const unsigned short* __restrict__ A, const unsigned short* __restrict__ BT,
        int M, int N, int K,
        const float* __restrict__ bias, const float* __restrict__ resid,
        float* __restrict__ outF, unsigned short* __restrict__ outB, float scale) {
    __shared__ __align__(16) unsigned short lds[2 * 128 * 64];
    unsigned short* lA = lds;
    unsigned short* lB = lds + 128 * 64;
    const int tid = threadIdx.x;
    const int lane = tid & 63;
    const int w = tid >> 6;
    const int wm = (w >> 1) * 64;
    const int wn = (w & 1) * 64;
    const int m0 = blockIdx.y * 128;
    const int n0 = blockIdx.x * 128;
    const int g = lane >> 4, lr = lane & 15;

    f32x4 acc[4][4];
#pragma unroll
    for (int i = 0; i < 4; ++i)
#pragma unroll
        for (int j = 0; j < 4; ++j)
            acc[i][j] = (f32x4){0.f, 0.f, 0.f, 0.f};

    // staging: LDS row r, slot s holds global chunk col (s - r) & 7  (swizzle)
    int rr[4], cc[4];
#pragma unroll
    for (int c = 0; c < 4; ++c) {
        const int chunk = tid + c * 256;
        rr[c] = chunk >> 3;
        cc[c] = (((chunk & 7) - rr[c]) & 7) * 8;
    }

    for (int k0 = 0; k0 < K; k0 += 64) {
        __syncthreads();
#pragma unroll
        for (int c = 0; c < 4; ++c) {
            async16(&A[(size_t)(m0 + rr[c]) * K + k0 + cc[c]], &lA[(size_t)(tid + c * 256) * 8]);
            async16(&BT[(size_t)(n0 + rr[c]) * K + k0 + cc[c]], &lB[(size_t)(tid + c * 256) * 8]);
        }
        __syncthreads();
#pragma unroll
        for (int ks = 0; ks < 2; ++ks) {
            bf16x8 af[4], bfr[4];
            const int cA = ks * 4 + g;
#pragma unroll
            for (int i = 0; i < 4; ++i) {
                const int rA = wm + i * 16 + lr;
                af[i] = *reinterpret_cast<const bf16x8*>(&lA[(rA * 8 + ((cA + rA) & 7)) * 8]);
                const int rB = wn + i * 16 + lr;
                bfr[i] = *reinterpret_cast<const bf16x8*>(&lB[(rB * 8 + ((cA + rB) & 7)) * 8]);
            }
#pragma unroll
            for (int mb = 0; mb < 4; ++mb)
#pragma unroll
                for (int nb = 0; nb < 4; ++nb)
                    acc[mb][nb] = MFMA16(af[mb], bfr[nb], acc[mb][nb]);
        }
    }

    // epilogue: C row = m0+wm+mb*16+g*4+r, col = n0+wn+nb*16+lr
#pragma unroll
    for (int mb = 0; mb < 4; ++mb) {
#pragma unroll
        for (int r = 0; r < 4; ++r) {
            const int m = m0 + wm + mb * 16 + g * 4 + r;
#pragma unroll
            for (int nb = 0; nb < 4; ++nb) {
                const int n = n0 + wn + nb * 16 + lr;
                float v = acc[mb][nb][r];
                if constexpr (EPI == 0) {
                    v *= scale;
                    const int b = m >> 11, s = m & 2047;
                    const int h = n >> 7, hd = n & 127;
                    outB[(((size_t)(b * 16 + h) * 2048 + s) << 7) + hd] = f2bf(v);
                } else if constexpr (EPI == 1) {
                    const size_t idx = (size_t)m * N + n;
                    outF[idx] = resid[idx] + v;
                } else if constexpr (EPI == 2) {
                    v += bias[n];
                    const float u = 0.7978845608028654f * (v + 0.044715f * v * v * v);
                    const float ge = 0.5f * v * (1.f + tanhf(u));
                    outB[(size_t)m * N + n] = f2bf(ge);
                } else {
                    const size_t idx = (size_t)m * N + n;
                    outF[idx] = v + bias[n] + resid[idx];
                }
            }
        }
    }
}

// ---------------------------------------------------------------------------
// Flash attention (FA2-style): 256 threads = 4 waves per block.
// Block = (bh, 64-row q-tile); wave w owns q-rows [qt*64 + w*16, +16).
// K-loop: 64-key tiles staged into LDS (K: [64][128], VT: [128][64]),
// XOR-chunk-swizzled; swizzle folded into global source addr so
// global_load_lds LDS dests stay lane-contiguous.
// Q,K in [B,H,S,HD] bf16 (Q pre-scaled), V in [B,H,HD,S] bf16. O -> [B,S,D].
// ---------------------------------------------------------------------------
__global__ void __launch_bounds__(256)
attn_kernel(const unsigned short* __restrict__ Q, const unsigned short* __restrict__ Kt,
            const unsigned short* __restrict__ VT, unsigned short* __restrict__ O) {
    __shared__ __align__(16) unsigned short lK[64 * 128];   // 16 KB [key][hd]
    __shared__ __align__(16) unsigned short lV[128 * 64];   // 16 KB [hd][key]
    __shared__ __align__(16) unsigned short lP[4][16 * 64]; //  8 KB per-wave P
    const int bh = blockIdx.y;
    const int qt = blockIdx.x;
    const int tid = threadIdx.x;
    const int w = tid >> 6;
    const int lane = tid & 63;
    const int g = lane >> 4, lr = lane & 15;
    const unsigned short* Qp = Q + ((size_t)bh * 2048 + qt * 64 + w * 16) * 128;
    const unsigned short* Kp = Kt + (size_t)bh * 2048 * 128;
    const unsigned short* Vp = VT + (size_t)bh * 128 * 2048;
    unsigned short* Pw = lP[w];

    // Q fragments: A[m=lr][k = c*32 + g*8 ..]
    bf16x8 qf[4];
#pragma unroll
    for (int c = 0; c < 4; ++c)
        qf[c] = *reinterpret_cast<const bf16x8*>(&Qp[lr * 128 + c * 32 + g * 8]);

    f32x4 o[8];
#pragma unroll
    for (int db = 0; db < 8; ++db) o[db] = (f32x4){0.f, 0.f, 0.f, 0.f};
    float mm[4] = {-1e30f, -1e30f, -1e30f, -1e30f};
    float ll[4] = {0.f, 0.f, 0.f, 0.f};

    // staging chunk maps (swizzle folded into global col)
    int kR[4], kJ[4], vR[4], vJ[4];
#pragma unroll
    for (int c = 0; c < 4; ++c) {
        const int chunk = tid + c * 256;
        kR[c] = chunk >> 4;                        // key row 0..63
        kJ[c] = ((chunk & 15) ^ (kR[c] & 15)) * 8; // hd elem offset
        vR[c] = chunk >> 3;                        // hd row 0..127
        vJ[c] = ((chunk & 7) ^ (vR[c] & 7)) * 8;   // key elem offset
    }

    for (int kt = 0; kt < 32; ++kt) {
        const int kb = kt * 64;
        __syncthreads();
#pragma unroll
        for (int c = 0; c < 4; ++c) {
            async16(&Kp[(size_t)(kb + kR[c]) * 128 + kJ[c]], &lK[(size_t)(tid + c * 256) * 8]);
            async16(&Vp[(size_t)vR[c] * 2048 + kb + vJ[c]], &lV[(size_t)(tid + c * 256) * 8]);
        }
        __syncthreads();

        // S = Q K^T for 4 key-blocks of 16
        f32x4 sc[4];
#pragma unroll
        for (int j16 = 0; j16 < 4; ++j16) sc[j16] = (f32x4){0.f, 0.f, 0.f, 0.f};
#pragma unroll
        for (int j16 = 0; j16 < 4; ++j16) {
            const int krow = j16 * 16 + lr;
#pragma unroll
            for (int c = 0; c < 4; ++c) {
                bf16x8 kf = *reinterpret_cast<const bf16x8*>(
                    &lK[krow * 128 + (((c * 4 + g) ^ lr) & 15) * 8]);
                sc[j16] = MFMA16(qf[c], kf, sc[j16]);
            }
        }

        // online softmax (rows g*4+r, 16 cols per group spread over lanes of g)
        float al[4];
        float pr[4][4];
#pragma unroll
        for (int r = 0; r < 4; ++r) {
            float mx = fmaxf(fmaxf(sc[0][r], sc[1][r]), fmaxf(sc[2][r], sc[3][r]));
            mx = fmaxf(mx, __shfl_xor(mx, 1));
            mx = fmaxf(mx, __shfl_xor(mx, 2));
            mx = fmaxf(mx, __shfl_xor(mx, 4));
            mx = fmaxf(mx, __shfl_xor(mx, 8));
            const float nm = fmaxf(mm[r], mx);
            al[r] = __expf(mm[r] - nm);
            float rs = 0.f;
#pragma unroll
            for (int j16 = 0; j16 < 4; ++j16) {
                pr[j16][r] = __expf(sc[j16][r] - nm);
                rs += pr[j16][r];
            }
            rs += __shfl_xor(rs, 1);
            rs += __shfl_xor(rs, 2);
            rs += __shfl_xor(rs, 4);
            rs += __shfl_xor(rs, 8);
            ll[r] = ll[r] * al[r] + rs;
            mm[r] = nm;
        }
#pragma unroll
        for (int db = 0; db < 8; ++db) {
            o[db][0] *= al[0]; o[db][1] *= al[1];
            o[db][2] *= al[2]; o[db][3] *= al[3];
        }

        // P (C-layout) -> LDS (swizzled [row][key]) -> A-layout fragments
#pragma unroll
        for (int j16 = 0; j16 < 4; ++j16)
#pragma unroll
            for (int r = 0; r < 4; ++r) {
                const int row = g * 4 + r;
                const int ch = j16 * 2 + (lr >> 3);
                Pw[row * 64 + ((ch ^ (row & 7)) * 8) + (lr & 7)] = f2bf(pr[j16][r]);
            }
        // wave-internal LDS write->read; compiler inserts lgkmcnt wait

        // O += P V
#pragma unroll
        for (int kk = 0; kk < 2; ++kk) {
            bf16x8 pf = *reinterpret_cast<const bf16x8*>(
                &Pw[lr * 64 + (((kk * 4 + g) ^ (lr & 7)) & 7) * 8]);
#pragma unroll
            for (int db = 0; db < 8; ++db) {
                const int vrow = db * 16 + lr;
                bf16x8 vf = *reinterpret_cast<const bf16x8*>(
                    &lV[vrow * 64 + (((kk * 4 + g) ^ (vrow & 7)) & 7) * 8]);
                o[db] = MFMA16(pf, vf, o[db]);
            }
        }
    }

    const int b = bh >> 4, h = bh & 15;
#pragma unroll
    for (int db = 0; db < 8; ++db)
#pragma unroll
        for (int r = 0; r < 4; ++r) {
            const int s = qt * 64 + w * 16 + g * 4 + r;
            const float v = o[db][r] / ll[r];
            O[((size_t)(b * 2048 + s)) * 2048 + h * 128 + db * 16 + lr] = f2bf(v);
        }
}

// ---------------------------------------------------------------------------
extern "C" void kernel_launch(void* const* d_in, const int* in_sizes, int n_in,
                              void* d_out, int out_size, void* d_ws, size_t ws_size,
                              hipStream_t stream) {
    const float* x    = (const float*)d_in[0];
    const float* wq   = (const float*)d_in[1];
    const float* wk   = (const float*)d_in[2];
    const float* wv   = (const float*)d_in[3];
    const float* wo   = (const float*)d_in[4];
    const float* ln1w = (const float*)d_in[5];
    const float* ln1b = (const float*)d_in[6];
    const float* ln2w = (const float*)d_in[7];
    const float* ln2b = (const float*)d_in[8];
    const float* fc1w = (const float*)d_in[9];
    const float* fc1b = (const float*)d_in[10];
    const float* fc2w = (const float*)d_in[11];
    const float* fc2b = (const float*)d_in[12];
    float* out = (float*)d_out;

    const size_t MB = 1024ull * 1024ull;
    if (ws_size < 200 * MB) return;  // diagnostic guard

    char* ws = (char*)d_ws;
    unsigned short* W8   = (unsigned short*)(ws + 0 * MB);    //  8 MB: wqT/wkT/wvT/woT (seq.)
    unsigned short* W32  = (unsigned short*)(ws + 8 * MB);    // 32 MB: fc1T then fc2T
    unsigned short* act  = (unsigned short*)(ws + 40 * MB);   // 32 MB: h -> attnO -> h2
    unsigned short* qb   = (unsigned short*)(ws + 72 * MB);   // 32 MB
    unsigned short* kb   = (unsigned short*)(ws + 104 * MB);  // 32 MB
    unsigned short* vb   = (unsigned short*)(ws + 136 * MB);  // 32 MB
    unsigned short* vtb  = (unsigned short*)(ws + 168 * MB);  // 32 MB
    unsigned short* mid  = qb;                                // 128 MB overlay (post-attn)
    float*          x1   = out;                               // x + attn proj in d_out

    const dim3 tb(32, 8);
    const float qscale = 0.08838834764831845f;

    // LN1: x -> h (bf16)
    ln_kernel<<<8192, 256, 0, stream>>>(x, ln1w, ln1b, act);

    // Q = h @ wq (scaled), head layout
    transpose_f32_bf16<<<dim3(64, 64), tb, 0, stream>>>(wq, W8, 2048, 2048);
    gemm_bt<0><<<dim3(16, 64), 256, 0, stream>>>(act, W8, 8192, 2048, 2048,
                                                 nullptr, nullptr, nullptr, qb, qscale);
    // K
    transpose_f32_bf16<<<dim3(64, 64), tb, 0, stream>>>(wk, W8, 2048, 2048);
    gemm_bt<0><<<dim3(16, 64), 256, 0, stream>>>(act, W8, 8192, 2048, 2048,
                                                 nullptr, nullptr, nullptr, kb, 1.f);
    // V
    transpose_f32_bf16<<<dim3(64, 64), tb, 0, stream>>>(wv, W8, 2048, 2048);
    gemm_bt<0><<<dim3(16, 64), 256, 0, stream>>>(act, W8, 8192, 2048, 2048,
                                                 nullptr, nullptr, nullptr, vb, 1.f);

    // V -> V^T per (b,h)
    transpose_v_bh<<<dim3(4, 64, 64), tb, 0, stream>>>(vb, vtb);

    // attention -> act ([B,S,D] bf16)
    attn_kernel<<<dim3(32, 64), 256, 0, stream>>>(qb, kb, vtb, act);

    // O-proj + residual -> x1 (= d_out, fp32)
    transpose_f32_bf16<<<dim3(64, 64), tb, 0, stream>>>(wo, W8, 2048, 2048);
    gemm_bt<1><<<dim3(16, 64), 256, 0, stream>>>(act, W8, 8192, 2048, 2048,
                                                 nullptr, x, x1, nullptr, 1.f);

    // LN2: x1 -> h2 (bf16, into act)
    ln_kernel<<<8192, 256, 0, stream>>>(x1, ln2w, ln2b, act);

    // FC1 + bias + gelu_new -> mid (bf16)
    transpose_f32_bf16<<<dim3(256, 64), tb, 0, stream>>>(fc1w, W32, 2048, 8192);
    gemm_bt<2><<<dim3(64, 64), 256, 0, stream>>>(act, W32, 8192, 8192, 2048,
                                                 fc1b, nullptr, nullptr, mid, 1.f);

    // FC2 + bias + residual(x1 in d_out) -> d_out (in-place RMW, one touch/elem)
    transpose_f32_bf16<<<dim3(64, 256), tb, 0, stream>>>(fc2w, W32, 8192, 2048);
    gemm_bt<3><<<dim3(16, 64), 256, 0, stream>>>(mid, W32, 8192, 2048, 8192,
                                                 fc2b, x1, out, nullptr, 1.f);
}